// Round 8
// baseline (98.950 us; speedup 1.0000x reference)
//
#include <hip/hip_runtime.h>
#include <stdint.h>

#define O_DIM 512
#define D_DIM 128
#define LR 0.01f
// 1 / (2 * sigma^2), sigma = 256 -> 1/131072
#define INV2SIG2 7.62939453125e-6f

typedef float f32x4 __attribute__((ext_vector_type(4)));

// ---------------- fast path ----------------
// ws layout: [0, 1 MiB) : dist[512][512] float
//
// Fused column-owner kernel, register-resident W:
//   block j (1024 threads, 16 waves, __launch_bounds__(1024,4) -> 1 block/CU,
//   VGPR cap 128) owns column W[:, j, :] (256 KB). Each thread holds a
//   4-float d-slice of 16 rows in registers (64 VGPR):
//     row b = s*32 + wave*2 + (lane>>5), d-slice d0 = (lane&31)*4.
//   Phase A: dist rows + S partials (5-step 32-lane shuffle reduce);
//   LDS reduce of S across waves; Phase B adds S to the register-held W and
//   streams out (nontemporal). W is read from HBM exactly once, never
//   re-read. R7 failed ONLY because the default VGPR cap (64) spilled wv[16]
//   (WRITE 279 MB); the (1024,4) bound raises the cap to 128 (~105 needed).
__global__ __launch_bounds__(1024, 4) void som_fused(
    const float* __restrict__ X,
    const float* __restrict__ W,
    float* __restrict__ dist,
    float* __restrict__ outW)
{
    const int j    = blockIdx.x;          // 0..511 column
    const int t    = threadIdx.x;         // 0..1023
    const int wave = t >> 6;              // 0..15
    const int lane = t & 63;
    const int g    = lane >> 5;           // row-subgroup 0..1
    const int i32  = lane & 31;           // d-slice index
    const int d0   = i32 * 4;             // floats [d0, d0+4)
    const int brow = wave * 2 + g;        // row base; b = s*32 + brow

    // ---- issue all 16 column loads (64 VGPR W-hold, 16 loads in flight) ----
    f32x4 wv[16];
    #pragma unroll
    for (int s = 0; s < 16; ++s) {
        const int b = s * 32 + brow;
        wv[s] = *(const f32x4*)(W + ((size_t)b * O_DIM + j) * D_DIM + d0);
    }

    // ---- phase A: dist + S partial ----
    f32x4 acc = {0.f, 0.f, 0.f, 0.f};
    #pragma unroll
    for (int s = 0; s < 16; ++s) {
        const int b = s * 32 + brow;
        const f32x4 x4 = *(const f32x4*)(X + (size_t)b * D_DIM + d0);
        const f32x4 dx = wv[s] - x4;
        float sum = dx.x * dx.x;
        sum = fmaf(dx.y, dx.y, sum);
        sum = fmaf(dx.z, dx.z, sum);
        sum = fmaf(dx.w, dx.w, sum);
        // reduce across the 32 lanes of this row
        sum += __shfl_xor(sum, 1, 64);
        sum += __shfl_xor(sum, 2, 64);
        sum += __shfl_xor(sum, 4, 64);
        sum += __shfl_xor(sum, 8, 64);
        sum += __shfl_xor(sum, 16, 64);

        if (i32 == 0) dist[(size_t)b * O_DIM + j] = sum;

        const float c = LR * __expf(-sum * INV2SIG2);
        acc -= c * dx;                    // += c * (x - w)
    }

    // ---- fold the two row-subgroups (lane ^ 32) ----
    acc.x += __shfl_xor(acc.x, 32, 64);
    acc.y += __shfl_xor(acc.y, 32, 64);
    acc.z += __shfl_xor(acc.z, 32, 64);
    acc.w += __shfl_xor(acc.w, 32, 64);

    // ---- LDS reduce across 16 waves ----
    __shared__ float sacc[16][D_DIM];
    __shared__ float sS[D_DIM];
    if (lane < 32) *(f32x4*)(&sacc[wave][d0]) = acc;
    __syncthreads();
    if (t < D_DIM) {
        float v = sacc[0][t];
        #pragma unroll
        for (int w = 1; w < 16; ++w) v += sacc[w][t];
        sS[t] = v;
    }
    __syncthreads();
    const f32x4 s4 = *(const f32x4*)(sS + d0);

    // ---- phase B: out[b, j, :] = W(reg) + S[j], no W re-read ----
    #pragma unroll
    for (int s = 0; s < 16; ++s) {
        const int b = s * 32 + brow;
        __builtin_nontemporal_store(
            wv[s] + s4, (f32x4*)(outW + ((size_t)b * O_DIM + j) * D_DIM + d0));
    }
}

// row-wise argmin over j for each b
__global__ __launch_bounds__(64) void som_argmin(
    const float* __restrict__ dist,
    float* __restrict__ out)
{
    const int b = blockIdx.x;
    const int lane = threadIdx.x;
    unsigned long long best = ~0ull;
    #pragma unroll
    for (int k = 0; k < 8; ++k) {
        const int jj = k * 64 + lane;
        const float s = dist[(size_t)b * O_DIM + jj];
        const unsigned long long key =
            ((unsigned long long)__float_as_uint(s) << 32) | (unsigned int)jj;
        best = key < best ? key : best;
    }
    #pragma unroll
    for (int m = 32; m >= 1; m >>= 1) {
        const unsigned long long o = __shfl_xor(best, m, 64);
        best = o < best ? o : best;
    }
    if (lane == 0) out[b] = (float)(unsigned int)(best & 0xFFFFFFFFull);
}

// ---------------- fallback path (atomics, small ws) ----------------

__global__ __launch_bounds__(256) void som_pass1_atomic(
    const float* __restrict__ X, const float* __restrict__ W,
    float* __restrict__ S, unsigned long long* __restrict__ wkey)
{
    const int j = blockIdx.x >> 2, chunk = blockIdx.x & 3;
    const int wave = threadIdx.x >> 6, lane = threadIdx.x & 63;
    const int d0 = lane * 2;
    float accx = 0.f, accy = 0.f;
    const int b_end = chunk * 128 + 128;
    for (int b = chunk * 128 + wave; b < b_end; b += 4) {
        const float2 w2 = *(const float2*)(W + ((size_t)b * O_DIM + j) * D_DIM + d0);
        const float2 x2 = *(const float2*)(X + (size_t)b * D_DIM + d0);
        const float dx = w2.x - x2.x, dy = w2.y - x2.y;
        float s = dx * dx + dy * dy;
        #pragma unroll
        for (int m = 32; m >= 1; m >>= 1) s += __shfl_xor(s, m, 64);
        if (lane == 0)
            atomicMin(&wkey[b], ((unsigned long long)__float_as_uint(s) << 32) | (unsigned)j);
        const float c = LR * __expf(-s * INV2SIG2);
        accx -= c * dx; accy -= c * dy;
    }
    __shared__ float sacc[D_DIM];
    if (threadIdx.x < D_DIM) sacc[threadIdx.x] = 0.f;
    __syncthreads();
    atomicAdd(&sacc[d0], accx); atomicAdd(&sacc[d0 + 1], accy);
    __syncthreads();
    if (threadIdx.x < D_DIM) atomicAdd(&S[(size_t)j * D_DIM + threadIdx.x], sacc[threadIdx.x]);
}

__global__ __launch_bounds__(256) void som_pass2_atomic(
    const float* __restrict__ W, const float* __restrict__ S,
    const unsigned long long* __restrict__ wkey, float* __restrict__ out)
{
    const size_t tid = (size_t)blockIdx.x * blockDim.x + threadIdx.x;
    if (tid < O_DIM) out[tid] = (float)(unsigned int)(wkey[tid] & 0xFFFFFFFFull);
    float* __restrict__ outW = out + O_DIM;
    const size_t total4 = (size_t)O_DIM * O_DIM * D_DIM / 4;
    const size_t stride = (size_t)gridDim.x * blockDim.x;
    for (size_t i = tid; i < total4; i += stride) {
        const size_t e = i * 4;
        const float4 w4 = *(const float4*)(W + e);
        const float4 s4 = *(const float4*)(S + (e & (size_t)(O_DIM * D_DIM - 1)));
        float4 o4 = {w4.x + s4.x, w4.y + s4.y, w4.z + s4.z, w4.w + s4.w};
        *(float4*)(outW + e) = o4;
    }
}

extern "C" void kernel_launch(void* const* d_in, const int* in_sizes, int n_in,
                              void* d_out, int out_size, void* d_ws, size_t ws_size,
                              hipStream_t stream)
{
    const float* X = (const float*)d_in[0];   // (512, 128)
    const float* W = (const float*)d_in[1];   // (512, 512, 128)
    float* out = (float*)d_out;               // 512 winners + 512*512*128 weights

    const size_t DIST_BYTES = (size_t)O_DIM * O_DIM * sizeof(float);   // 1 MiB

    if (ws_size >= DIST_BYTES) {
        float* dist = (float*)d_ws;
        som_fused <<<dim3(512), dim3(1024), 0, stream>>>(X, W, dist, out + O_DIM);
        som_argmin<<<dim3(512), dim3(64),   0, stream>>>(dist, out);
    } else {
        float* S = (float*)d_ws;
        unsigned long long* wkey =
            (unsigned long long*)((char*)d_ws + (size_t)O_DIM * D_DIM * sizeof(float));
        hipMemsetAsync(S, 0, (size_t)O_DIM * D_DIM * sizeof(float), stream);
        hipMemsetAsync(wkey, 0xFF, (size_t)O_DIM * sizeof(unsigned long long), stream);
        som_pass1_atomic<<<dim3(2048), dim3(256), 0, stream>>>(X, W, S, wkey);
        som_pass2_atomic<<<dim3(2048), dim3(256), 0, stream>>>(W, S, wkey, out);
    }
}

// Round 9
// 95.690 us; speedup vs baseline: 1.0341x; 1.0341x over previous
//
#include <hip/hip_runtime.h>
#include <stdint.h>

#define O_DIM 512
#define D_DIM 128
#define LR 0.01f
// 1 / (2 * sigma^2), sigma = 256 -> 1/131072
#define INV2SIG2 7.62939453125e-6f

typedef float f32x4 __attribute__((ext_vector_type(4)));

// ---------------- fast path ----------------
// ws layout: [0, 1 MiB) : dist[512][512] float
//
// Fused column-owner kernel, register-resident W:
//   block j (1024 threads, 16 waves) owns column W[:, j, :] (256 KB).
//   Each thread holds a 4-float d-slice of 16 rows in registers (64 VGPR):
//     row b = s*32 + wave*2 + (lane>>5), d-slice d0 = (lane&31)*4.
//   W is read from HBM exactly once and never re-read.
//
//   R7/R8 lesson: __launch_bounds__(1024,4) does NOT cap registers — the
//   2nd arg is only a MIN waves/EU; the allocator still targeted 8 waves/EU,
//   clamped to 64 VGPR and spilled wv[16] (WRITE 279 MB vs 140 ideal).
//   amdgpu_waves_per_eu(4,4) sets min=max=4 -> 1 block/CU -> 128-VGPR cap.
__global__ void
__launch_bounds__(1024)
__attribute__((amdgpu_waves_per_eu(4, 4)))
som_fused(
    const float* __restrict__ X,
    const float* __restrict__ W,
    float* __restrict__ dist,
    float* __restrict__ outW)
{
    const int j    = blockIdx.x;          // 0..511 column
    const int t    = threadIdx.x;         // 0..1023
    const int wave = t >> 6;              // 0..15
    const int lane = t & 63;
    const int g    = lane >> 5;           // row-subgroup 0..1
    const int i32  = lane & 31;           // d-slice index
    const int d0   = i32 * 4;             // floats [d0, d0+4)
    const int brow = wave * 2 + g;        // row base; b = s*32 + brow

    // ---- issue all 16 column loads (64 VGPR W-hold, 16 loads in flight) ----
    f32x4 wv[16];
    #pragma unroll
    for (int s = 0; s < 16; ++s) {
        const int b = s * 32 + brow;
        wv[s] = *(const f32x4*)(W + ((size_t)b * O_DIM + j) * D_DIM + d0);
    }

    // ---- phase A: dist + S partial ----
    f32x4 acc = {0.f, 0.f, 0.f, 0.f};
    #pragma unroll
    for (int s = 0; s < 16; ++s) {
        const int b = s * 32 + brow;
        const f32x4 x4 = *(const f32x4*)(X + (size_t)b * D_DIM + d0);
        const f32x4 dx = wv[s] - x4;
        float sum = dx.x * dx.x;
        sum = fmaf(dx.y, dx.y, sum);
        sum = fmaf(dx.z, dx.z, sum);
        sum = fmaf(dx.w, dx.w, sum);
        // reduce across the 32 lanes of this row
        sum += __shfl_xor(sum, 1, 64);
        sum += __shfl_xor(sum, 2, 64);
        sum += __shfl_xor(sum, 4, 64);
        sum += __shfl_xor(sum, 8, 64);
        sum += __shfl_xor(sum, 16, 64);

        if (i32 == 0) dist[(size_t)b * O_DIM + j] = sum;

        const float c = LR * __expf(-sum * INV2SIG2);
        acc -= c * dx;                    // += c * (x - w)
    }

    // ---- fold the two row-subgroups (lane ^ 32) ----
    acc.x += __shfl_xor(acc.x, 32, 64);
    acc.y += __shfl_xor(acc.y, 32, 64);
    acc.z += __shfl_xor(acc.z, 32, 64);
    acc.w += __shfl_xor(acc.w, 32, 64);

    // ---- LDS reduce across 16 waves ----
    __shared__ float sacc[16][D_DIM];
    __shared__ float sS[D_DIM];
    if (lane < 32) *(f32x4*)(&sacc[wave][d0]) = acc;
    __syncthreads();
    if (t < D_DIM) {
        float v = sacc[0][t];
        #pragma unroll
        for (int w = 1; w < 16; ++w) v += sacc[w][t];
        sS[t] = v;
    }
    __syncthreads();
    const f32x4 s4 = *(const f32x4*)(sS + d0);

    // ---- phase B: out[b, j, :] = W(reg) + S[j], no W re-read ----
    #pragma unroll
    for (int s = 0; s < 16; ++s) {
        const int b = s * 32 + brow;
        __builtin_nontemporal_store(
            wv[s] + s4, (f32x4*)(outW + ((size_t)b * O_DIM + j) * D_DIM + d0));
    }
}

// row-wise argmin over j for each b
__global__ __launch_bounds__(64) void som_argmin(
    const float* __restrict__ dist,
    float* __restrict__ out)
{
    const int b = blockIdx.x;
    const int lane = threadIdx.x;
    unsigned long long best = ~0ull;
    #pragma unroll
    for (int k = 0; k < 8; ++k) {
        const int jj = k * 64 + lane;
        const float s = dist[(size_t)b * O_DIM + jj];
        const unsigned long long key =
            ((unsigned long long)__float_as_uint(s) << 32) | (unsigned int)jj;
        best = key < best ? key : best;
    }
    #pragma unroll
    for (int m = 32; m >= 1; m >>= 1) {
        const unsigned long long o = __shfl_xor(best, m, 64);
        best = o < best ? o : best;
    }
    if (lane == 0) out[b] = (float)(unsigned int)(best & 0xFFFFFFFFull);
}

// ---------------- fallback path (atomics, small ws) ----------------

__global__ __launch_bounds__(256) void som_pass1_atomic(
    const float* __restrict__ X, const float* __restrict__ W,
    float* __restrict__ S, unsigned long long* __restrict__ wkey)
{
    const int j = blockIdx.x >> 2, chunk = blockIdx.x & 3;
    const int wave = threadIdx.x >> 6, lane = threadIdx.x & 63;
    const int d0 = lane * 2;
    float accx = 0.f, accy = 0.f;
    const int b_end = chunk * 128 + 128;
    for (int b = chunk * 128 + wave; b < b_end; b += 4) {
        const float2 w2 = *(const float2*)(W + ((size_t)b * O_DIM + j) * D_DIM + d0);
        const float2 x2 = *(const float2*)(X + (size_t)b * D_DIM + d0);
        const float dx = w2.x - x2.x, dy = w2.y - x2.y;
        float s = dx * dx + dy * dy;
        #pragma unroll
        for (int m = 32; m >= 1; m >>= 1) s += __shfl_xor(s, m, 64);
        if (lane == 0)
            atomicMin(&wkey[b], ((unsigned long long)__float_as_uint(s) << 32) | (unsigned)j);
        const float c = LR * __expf(-s * INV2SIG2);
        accx -= c * dx; accy -= c * dy;
    }
    __shared__ float sacc[D_DIM];
    if (threadIdx.x < D_DIM) sacc[threadIdx.x] = 0.f;
    __syncthreads();
    atomicAdd(&sacc[d0], accx); atomicAdd(&sacc[d0 + 1], accy);
    __syncthreads();
    if (threadIdx.x < D_DIM) atomicAdd(&S[(size_t)j * D_DIM + threadIdx.x], sacc[threadIdx.x]);
}

__global__ __launch_bounds__(256) void som_pass2_atomic(
    const float* __restrict__ W, const float* __restrict__ S,
    const unsigned long long* __restrict__ wkey, float* __restrict__ out)
{
    const size_t tid = (size_t)blockIdx.x * blockDim.x + threadIdx.x;
    if (tid < O_DIM) out[tid] = (float)(unsigned int)(wkey[tid] & 0xFFFFFFFFull);
    float* __restrict__ outW = out + O_DIM;
    const size_t total4 = (size_t)O_DIM * O_DIM * D_DIM / 4;
    const size_t stride = (size_t)gridDim.x * blockDim.x;
    for (size_t i = tid; i < total4; i += stride) {
        const size_t e = i * 4;
        const float4 w4 = *(const float4*)(W + e);
        const float4 s4 = *(const float4*)(S + (e & (size_t)(O_DIM * D_DIM - 1)));
        float4 o4 = {w4.x + s4.x, w4.y + s4.y, w4.z + s4.z, w4.w + s4.w};
        *(float4*)(outW + e) = o4;
    }
}

extern "C" void kernel_launch(void* const* d_in, const int* in_sizes, int n_in,
                              void* d_out, int out_size, void* d_ws, size_t ws_size,
                              hipStream_t stream)
{
    const float* X = (const float*)d_in[0];   // (512, 128)
    const float* W = (const float*)d_in[1];   // (512, 512, 128)
    float* out = (float*)d_out;               // 512 winners + 512*512*128 weights

    const size_t DIST_BYTES = (size_t)O_DIM * O_DIM * sizeof(float);   // 1 MiB

    if (ws_size >= DIST_BYTES) {
        float* dist = (float*)d_ws;
        som_fused <<<dim3(512), dim3(1024), 0, stream>>>(X, W, dist, out + O_DIM);
        som_argmin<<<dim3(512), dim3(64),   0, stream>>>(dist, out);
    } else {
        float* S = (float*)d_ws;
        unsigned long long* wkey =
            (unsigned long long*)((char*)d_ws + (size_t)O_DIM * D_DIM * sizeof(float));
        hipMemsetAsync(S, 0, (size_t)O_DIM * D_DIM * sizeof(float), stream);
        hipMemsetAsync(wkey, 0xFF, (size_t)O_DIM * sizeof(unsigned long long), stream);
        som_pass1_atomic<<<dim3(2048), dim3(256), 0, stream>>>(X, W, S, wkey);
        som_pass2_atomic<<<dim3(2048), dim3(256), 0, stream>>>(W, S, wkey, out);
    }
}

// Round 10
// 67.417 us; speedup vs baseline: 1.4677x; 1.4194x over previous
//
#include <hip/hip_runtime.h>
#include <stdint.h>

#define O_DIM 512
#define D_DIM 128
#define LR 0.01f
// 1 / (2 * sigma^2), sigma = 256 -> 1/131072
#define INV2SIG2 7.62939453125e-6f

#define LDS_ROWS 288   // rows of the column cached in LDS (144 KB)
#define LDS_GRPS 36    // LDS_ROWS / 8

typedef float f32x4 __attribute__((ext_vector_type(4)));

// ---------------- fast path ----------------
// ws layout: [0, 1 MiB) : dist[512][512] float
//
// Fused column-owner kernel, LDS-resident W (rows 0..287):
//   block j (256 threads, 4 waves) owns column W[:, j, :].
//   ~150 KB LDS forces 1 block/CU -> allocator's occupancy target drops to
//   1 wave/SIMD -> VGPR budget relaxes (R5/R7/R8/R9 all hit the 64-VGPR
//   occupancy clamp with small-LDS blocks and spilled; LDS sidesteps it).
//   Phase A: stream all 512 rows through registers (batch-8 -> 16 loads in
//   flight/thread), compute dist + S partials; rows < 288 are also
//   ds_written to LDS (no extra global traffic).
//   Phase B: rows < 288 re-read from LDS (zero memory-system cost);
//   rows >= 288 re-read from L3 (only 60 MB grid-wide instead of 134 MB).
__global__ __launch_bounds__(256) void som_fused(
    const float* __restrict__ X,
    const float* __restrict__ W,
    float* __restrict__ dist,
    float* __restrict__ outW)
{
    const int j    = blockIdx.x;          // 0..511 column
    const int t    = threadIdx.x;
    const int wave = t >> 6;              // 0..3
    const int lane = t & 63;
    const int g    = lane >> 5;           // row-subgroup 0..1
    const int i32  = lane & 31;           // d-slice index
    const int d0   = i32 * 4;             // floats [d0, d0+4)
    const int rb   = wave * 2 + g;        // row-in-group; b = grp*8 + rb

    __shared__ float ldsW[LDS_ROWS * D_DIM];   // 147456 B
    __shared__ float sacc[4][D_DIM];           // 2048 B
    __shared__ float sS[D_DIM];                // 512 B

    f32x4 acc = {0.f, 0.f, 0.f, 0.f};

    // ---------------- phase A: 8 batches x 8 groups (64 rows/batch) ----------------
    for (int bt = 0; bt < 8; ++bt) {
        f32x4 wv[8], xv[8];
        #pragma unroll
        for (int u = 0; u < 8; ++u) {
            const int b = (bt * 8 + u) * 8 + rb;
            wv[u] = *(const f32x4*)(W + ((size_t)b * O_DIM + j) * D_DIM + d0);
            xv[u] = *(const f32x4*)(X + (size_t)b * D_DIM + d0);
        }
        #pragma unroll
        for (int u = 0; u < 8; ++u) {
            const int b = (bt * 8 + u) * 8 + rb;
            const f32x4 dx = wv[u] - xv[u];
            float sum = dx.x * dx.x;
            sum = fmaf(dx.y, dx.y, sum);
            sum = fmaf(dx.z, dx.z, sum);
            sum = fmaf(dx.w, dx.w, sum);
            // reduce across the 32 lanes of this row
            sum += __shfl_xor(sum, 1, 64);
            sum += __shfl_xor(sum, 2, 64);
            sum += __shfl_xor(sum, 4, 64);
            sum += __shfl_xor(sum, 8, 64);
            sum += __shfl_xor(sum, 16, 64);

            if (i32 == 0) dist[(size_t)b * O_DIM + j] = sum;

            const float c = LR * __expf(-sum * INV2SIG2);
            acc -= c * dx;                    // += c * (x - w)

            if (b < LDS_ROWS)                 // wave-uniform condition
                *(f32x4*)(&ldsW[b * D_DIM + d0]) = wv[u];
        }
    }

    // ---- fold the two row-subgroups (lane ^ 32) ----
    acc.x += __shfl_xor(acc.x, 32, 64);
    acc.y += __shfl_xor(acc.y, 32, 64);
    acc.z += __shfl_xor(acc.z, 32, 64);
    acc.w += __shfl_xor(acc.w, 32, 64);

    if (lane < 32) *(f32x4*)(&sacc[wave][d0]) = acc;
    __syncthreads();
    if (t < D_DIM) sS[t] = sacc[0][t] + sacc[1][t] + sacc[2][t] + sacc[3][t];
    __syncthreads();
    const f32x4 s4 = *(const f32x4*)(sS + d0);

    // ---------------- phase B-lower: rows 0..287 from LDS ----------------
    #pragma unroll 4
    for (int grp = 0; grp < LDS_GRPS; ++grp) {
        const int b = grp * 8 + rb;
        const f32x4 wv = *(const f32x4*)(&ldsW[b * D_DIM + d0]);
        __builtin_nontemporal_store(
            wv + s4, (f32x4*)(outW + ((size_t)b * O_DIM + j) * D_DIM + d0));
    }
    // ---------------- phase B-upper: rows 288..511 from L3, batch 4 ----------------
    for (int bt = 0; bt < 7; ++bt) {
        f32x4 wv[4];
        #pragma unroll
        for (int u = 0; u < 4; ++u) {
            const int b = (LDS_GRPS + bt * 4 + u) * 8 + rb;
            wv[u] = *(const f32x4*)(W + ((size_t)b * O_DIM + j) * D_DIM + d0);
        }
        #pragma unroll
        for (int u = 0; u < 4; ++u) {
            const int b = (LDS_GRPS + bt * 4 + u) * 8 + rb;
            __builtin_nontemporal_store(
                wv[u] + s4, (f32x4*)(outW + ((size_t)b * O_DIM + j) * D_DIM + d0));
        }
    }
}

// row-wise argmin over j for each b
__global__ __launch_bounds__(64) void som_argmin(
    const float* __restrict__ dist,
    float* __restrict__ out)
{
    const int b = blockIdx.x;
    const int lane = threadIdx.x;
    unsigned long long best = ~0ull;
    #pragma unroll
    for (int k = 0; k < 8; ++k) {
        const int jj = k * 64 + lane;
        const float s = dist[(size_t)b * O_DIM + jj];
        const unsigned long long key =
            ((unsigned long long)__float_as_uint(s) << 32) | (unsigned int)jj;
        best = key < best ? key : best;
    }
    #pragma unroll
    for (int m = 32; m >= 1; m >>= 1) {
        const unsigned long long o = __shfl_xor(best, m, 64);
        best = o < best ? o : best;
    }
    if (lane == 0) out[b] = (float)(unsigned int)(best & 0xFFFFFFFFull);
}

// ---------------- fallback path (atomics, small ws) ----------------

__global__ __launch_bounds__(256) void som_pass1_atomic(
    const float* __restrict__ X, const float* __restrict__ W,
    float* __restrict__ S, unsigned long long* __restrict__ wkey)
{
    const int j = blockIdx.x >> 2, chunk = blockIdx.x & 3;
    const int wave = threadIdx.x >> 6, lane = threadIdx.x & 63;
    const int d0 = lane * 2;
    float accx = 0.f, accy = 0.f;
    const int b_end = chunk * 128 + 128;
    for (int b = chunk * 128 + wave; b < b_end; b += 4) {
        const float2 w2 = *(const float2*)(W + ((size_t)b * O_DIM + j) * D_DIM + d0);
        const float2 x2 = *(const float2*)(X + (size_t)b * D_DIM + d0);
        const float dx = w2.x - x2.x, dy = w2.y - x2.y;
        float s = dx * dx + dy * dy;
        #pragma unroll
        for (int m = 32; m >= 1; m >>= 1) s += __shfl_xor(s, m, 64);
        if (lane == 0)
            atomicMin(&wkey[b], ((unsigned long long)__float_as_uint(s) << 32) | (unsigned)j);
        const float c = LR * __expf(-s * INV2SIG2);
        accx -= c * dx; accy -= c * dy;
    }
    __shared__ float sacc[D_DIM];
    if (threadIdx.x < D_DIM) sacc[threadIdx.x] = 0.f;
    __syncthreads();
    atomicAdd(&sacc[d0], accx); atomicAdd(&sacc[d0 + 1], accy);
    __syncthreads();
    if (threadIdx.x < D_DIM) atomicAdd(&S[(size_t)j * D_DIM + threadIdx.x], sacc[threadIdx.x]);
}

__global__ __launch_bounds__(256) void som_pass2_atomic(
    const float* __restrict__ W, const float* __restrict__ S,
    const unsigned long long* __restrict__ wkey, float* __restrict__ out)
{
    const size_t tid = (size_t)blockIdx.x * blockDim.x + threadIdx.x;
    if (tid < O_DIM) out[tid] = (float)(unsigned int)(wkey[tid] & 0xFFFFFFFFull);
    float* __restrict__ outW = out + O_DIM;
    const size_t total4 = (size_t)O_DIM * O_DIM * D_DIM / 4;
    const size_t stride = (size_t)gridDim.x * blockDim.x;
    for (size_t i = tid; i < total4; i += stride) {
        const size_t e = i * 4;
        const float4 w4 = *(const float4*)(W + e);
        const float4 s4 = *(const float4*)(S + (e & (size_t)(O_DIM * D_DIM - 1)));
        float4 o4 = {w4.x + s4.x, w4.y + s4.y, w4.z + s4.z, w4.w + s4.w};
        *(float4*)(outW + e) = o4;
    }
}

extern "C" void kernel_launch(void* const* d_in, const int* in_sizes, int n_in,
                              void* d_out, int out_size, void* d_ws, size_t ws_size,
                              hipStream_t stream)
{
    const float* X = (const float*)d_in[0];   // (512, 128)
    const float* W = (const float*)d_in[1];   // (512, 512, 128)
    float* out = (float*)d_out;               // 512 winners + 512*512*128 weights

    const size_t DIST_BYTES = (size_t)O_DIM * O_DIM * sizeof(float);   // 1 MiB

    if (ws_size >= DIST_BYTES) {
        float* dist = (float*)d_ws;
        som_fused <<<dim3(512), dim3(256), 0, stream>>>(X, W, dist, out + O_DIM);
        som_argmin<<<dim3(512), dim3(64),  0, stream>>>(dist, out);
    } else {
        float* S = (float*)d_ws;
        unsigned long long* wkey =
            (unsigned long long*)((char*)d_ws + (size_t)O_DIM * D_DIM * sizeof(float));
        hipMemsetAsync(S, 0, (size_t)O_DIM * D_DIM * sizeof(float), stream);
        hipMemsetAsync(wkey, 0xFF, (size_t)O_DIM * sizeof(unsigned long long), stream);
        som_pass1_atomic<<<dim3(2048), dim3(256), 0, stream>>>(X, W, S, wkey);
        som_pass2_atomic<<<dim3(2048), dim3(256), 0, stream>>>(W, S, wkey, out);
    }
}

// Round 11
// 56.476 us; speedup vs baseline: 1.7521x; 1.1937x over previous
//
#include <hip/hip_runtime.h>
#include <stdint.h>

#define O_DIM 512
#define D_DIM 128
#define LR 0.01f
// 1 / (2 * sigma^2), sigma = 256 -> 1/131072
#define INV2SIG2 7.62939453125e-6f

#define LDS_ROWS 288   // rows of the column cached in LDS (144 KB); 288 % 16 == 0
#define LDS_GRPS 18    // LDS_ROWS / 16

typedef float f32x4 __attribute__((ext_vector_type(4)));

// ---------------- fast path ----------------
// ws layout: [0, 1 MiB) : dist[512][512] float
//
// Fused column-owner kernel, LDS-resident W (rows 0..287):
//   block j (512 threads, 8 waves) owns column W[:, j, :].
//   ~148 KB LDS forces 1 block/CU -> allocator VGPR budget relaxes (R10:
//   188 VGPR, no spill). R10 ran 256 threads = 1 wave/SIMD and was
//   latency-bound (3.7 TB/s, VALUBusy 9%); 512 threads = 2 waves/SIMD
//   doubles latency hiding at unchanged traffic.
//   Phase A: stream all 512 rows (batch-8 -> 16 loads in flight/thread),
//   compute dist + S partials; rows < 288 also ds_written to LDS.
//   Phase B: rows < 288 from LDS (free); rows >= 288 re-read via L3.
__global__ __launch_bounds__(512) void som_fused(
    const float* __restrict__ X,
    const float* __restrict__ W,
    float* __restrict__ dist,
    float* __restrict__ outW)
{
    const int j    = blockIdx.x;          // 0..511 column
    const int t    = threadIdx.x;
    const int wave = t >> 6;              // 0..7
    const int lane = t & 63;
    const int g    = lane >> 5;           // row-subgroup 0..1
    const int i32  = lane & 31;           // d-slice index
    const int d0   = i32 * 4;             // floats [d0, d0+4)
    const int rb   = wave * 2 + g;        // row-in-group 0..15; b = grp*16 + rb

    __shared__ float ldsW[LDS_ROWS * D_DIM];   // 147456 B
    __shared__ float sacc[8][D_DIM];           // 4096 B
    __shared__ float sS[D_DIM];                // 512 B

    f32x4 acc = {0.f, 0.f, 0.f, 0.f};

    // ---------------- phase A: 4 batches x 8 groups (128 rows/batch) ----------------
    for (int bt = 0; bt < 4; ++bt) {
        f32x4 wv[8], xv[8];
        #pragma unroll
        for (int u = 0; u < 8; ++u) {
            const int b = (bt * 8 + u) * 16 + rb;
            wv[u] = *(const f32x4*)(W + ((size_t)b * O_DIM + j) * D_DIM + d0);
            xv[u] = *(const f32x4*)(X + (size_t)b * D_DIM + d0);
        }
        #pragma unroll
        for (int u = 0; u < 8; ++u) {
            const int b = (bt * 8 + u) * 16 + rb;
            const f32x4 dx = wv[u] - xv[u];
            float sum = dx.x * dx.x;
            sum = fmaf(dx.y, dx.y, sum);
            sum = fmaf(dx.z, dx.z, sum);
            sum = fmaf(dx.w, dx.w, sum);
            // reduce across the 32 lanes of this row
            sum += __shfl_xor(sum, 1, 64);
            sum += __shfl_xor(sum, 2, 64);
            sum += __shfl_xor(sum, 4, 64);
            sum += __shfl_xor(sum, 8, 64);
            sum += __shfl_xor(sum, 16, 64);

            if (i32 == 0) dist[(size_t)b * O_DIM + j] = sum;

            const float c = LR * __expf(-sum * INV2SIG2);
            acc -= c * dx;                    // += c * (x - w)

            if (b < LDS_ROWS)                 // group-uniform (288 % 16 == 0)
                *(f32x4*)(&ldsW[b * D_DIM + d0]) = wv[u];
        }
    }

    // ---- fold the two row-subgroups (lane ^ 32) ----
    acc.x += __shfl_xor(acc.x, 32, 64);
    acc.y += __shfl_xor(acc.y, 32, 64);
    acc.z += __shfl_xor(acc.z, 32, 64);
    acc.w += __shfl_xor(acc.w, 32, 64);

    if (lane < 32) *(f32x4*)(&sacc[wave][d0]) = acc;
    __syncthreads();
    if (t < D_DIM) {
        float v = sacc[0][t];
        #pragma unroll
        for (int w = 1; w < 8; ++w) v += sacc[w][t];
        sS[t] = v;
    }
    __syncthreads();
    const f32x4 s4 = *(const f32x4*)(sS + d0);

    // ---------------- phase B-lower: rows 0..287 from LDS ----------------
    #pragma unroll 4
    for (int grp = 0; grp < LDS_GRPS; ++grp) {
        const int b = grp * 16 + rb;
        const f32x4 wv = *(const f32x4*)(&ldsW[b * D_DIM + d0]);
        __builtin_nontemporal_store(
            wv + s4, (f32x4*)(outW + ((size_t)b * O_DIM + j) * D_DIM + d0));
    }
    // ---------------- phase B-upper: rows 288..511 from L3, batch 4 ----------------
    for (int bt = 0; bt < 3; ++bt) {
        f32x4 wv[4];
        const int n = (bt < 2) ? 4 : 6;   // 18 + 4+4+6 = 32 groups
        f32x4 wx[6];
        #pragma unroll
        for (int u = 0; u < 6; ++u) {
            if (u < n) {
                const int b = (LDS_GRPS + bt * 4 + u) * 16 + rb;
                wx[u] = *(const f32x4*)(W + ((size_t)b * O_DIM + j) * D_DIM + d0);
            }
        }
        #pragma unroll
        for (int u = 0; u < 6; ++u) {
            if (u < n) {
                const int b = (LDS_GRPS + bt * 4 + u) * 16 + rb;
                __builtin_nontemporal_store(
                    wx[u] + s4, (f32x4*)(outW + ((size_t)b * O_DIM + j) * D_DIM + d0));
            }
        }
        (void)wv;
    }
}

// row-wise argmin over j for each b
__global__ __launch_bounds__(64) void som_argmin(
    const float* __restrict__ dist,
    float* __restrict__ out)
{
    const int b = blockIdx.x;
    const int lane = threadIdx.x;
    unsigned long long best = ~0ull;
    #pragma unroll
    for (int k = 0; k < 8; ++k) {
        const int jj = k * 64 + lane;
        const float s = dist[(size_t)b * O_DIM + jj];
        const unsigned long long key =
            ((unsigned long long)__float_as_uint(s) << 32) | (unsigned int)jj;
        best = key < best ? key : best;
    }
    #pragma unroll
    for (int m = 32; m >= 1; m >>= 1) {
        const unsigned long long o = __shfl_xor(best, m, 64);
        best = o < best ? o : best;
    }
    if (lane == 0) out[b] = (float)(unsigned int)(best & 0xFFFFFFFFull);
}

// ---------------- fallback path (atomics, small ws) ----------------

__global__ __launch_bounds__(256) void som_pass1_atomic(
    const float* __restrict__ X, const float* __restrict__ W,
    float* __restrict__ S, unsigned long long* __restrict__ wkey)
{
    const int j = blockIdx.x >> 2, chunk = blockIdx.x & 3;
    const int wave = threadIdx.x >> 6, lane = threadIdx.x & 63;
    const int d0 = lane * 2;
    float accx = 0.f, accy = 0.f;
    const int b_end = chunk * 128 + 128;
    for (int b = chunk * 128 + wave; b < b_end; b += 4) {
        const float2 w2 = *(const float2*)(W + ((size_t)b * O_DIM + j) * D_DIM + d0);
        const float2 x2 = *(const float2*)(X + (size_t)b * D_DIM + d0);
        const float dx = w2.x - x2.x, dy = w2.y - x2.y;
        float s = dx * dx + dy * dy;
        #pragma unroll
        for (int m = 32; m >= 1; m >>= 1) s += __shfl_xor(s, m, 64);
        if (lane == 0)
            atomicMin(&wkey[b], ((unsigned long long)__float_as_uint(s) << 32) | (unsigned)j);
        const float c = LR * __expf(-s * INV2SIG2);
        accx -= c * dx; accy -= c * dy;
    }
    __shared__ float sacc[D_DIM];
    if (threadIdx.x < D_DIM) sacc[threadIdx.x] = 0.f;
    __syncthreads();
    atomicAdd(&sacc[d0], accx); atomicAdd(&sacc[d0 + 1], accy);
    __syncthreads();
    if (threadIdx.x < D_DIM) atomicAdd(&S[(size_t)j * D_DIM + threadIdx.x], sacc[threadIdx.x]);
}

__global__ __launch_bounds__(256) void som_pass2_atomic(
    const float* __restrict__ W, const float* __restrict__ S,
    const unsigned long long* __restrict__ wkey, float* __restrict__ out)
{
    const size_t tid = (size_t)blockIdx.x * blockDim.x + threadIdx.x;
    if (tid < O_DIM) out[tid] = (float)(unsigned int)(wkey[tid] & 0xFFFFFFFFull);
    float* __restrict__ outW = out + O_DIM;
    const size_t total4 = (size_t)O_DIM * O_DIM * D_DIM / 4;
    const size_t stride = (size_t)gridDim.x * blockDim.x;
    for (size_t i = tid; i < total4; i += stride) {
        const size_t e = i * 4;
        const float4 w4 = *(const float4*)(W + e);
        const float4 s4 = *(const float4*)(S + (e & (size_t)(O_DIM * D_DIM - 1)));
        float4 o4 = {w4.x + s4.x, w4.y + s4.y, w4.z + s4.z, w4.w + s4.w};
        *(float4*)(outW + e) = o4;
    }
}

extern "C" void kernel_launch(void* const* d_in, const int* in_sizes, int n_in,
                              void* d_out, int out_size, void* d_ws, size_t ws_size,
                              hipStream_t stream)
{
    const float* X = (const float*)d_in[0];   // (512, 128)
    const float* W = (const float*)d_in[1];   // (512, 512, 128)
    float* out = (float*)d_out;               // 512 winners + 512*512*128 weights

    const size_t DIST_BYTES = (size_t)O_DIM * O_DIM * sizeof(float);   // 1 MiB

    if (ws_size >= DIST_BYTES) {
        float* dist = (float*)d_ws;
        som_fused <<<dim3(512), dim3(512), 0, stream>>>(X, W, dist, out + O_DIM);
        som_argmin<<<dim3(512), dim3(64),  0, stream>>>(dist, out);
    } else {
        float* S = (float*)d_ws;
        unsigned long long* wkey =
            (unsigned long long*)((char*)d_ws + (size_t)O_DIM * D_DIM * sizeof(float));
        hipMemsetAsync(S, 0, (size_t)O_DIM * D_DIM * sizeof(float), stream);
        hipMemsetAsync(wkey, 0xFF, (size_t)O_DIM * sizeof(unsigned long long), stream);
        som_pass1_atomic<<<dim3(2048), dim3(256), 0, stream>>>(X, W, S, wkey);
        som_pass2_atomic<<<dim3(2048), dim3(256), 0, stream>>>(W, S, wkey, out);
    }
}

// Round 12
// 56.182 us; speedup vs baseline: 1.7613x; 1.0052x over previous
//
#include <hip/hip_runtime.h>
#include <stdint.h>

#define O_DIM 512
#define D_DIM 128
#define LR 0.01f
// 1 / (2 * sigma^2), sigma = 256 -> 1/131072
#define INV2SIG2 7.62939453125e-6f

#define LDS_ROWS 288   // rows of the column cached in LDS (144 KB); 288 % 32 == 0
#define LDS_GRPS 9     // LDS_ROWS / 32

typedef float f32x4 __attribute__((ext_vector_type(4)));

// ---------------- fast path ----------------
// ws layout: [0, 1 MiB) : dist[512][512] float
//
// Fused column-owner kernel, LDS-resident W (rows 0..287):
//   block j (1024 threads, 16 waves) owns column W[:, j, :].
//   152 KB LDS makes 1 block/CU the provable max -> allocator targets
//   4 waves/EU -> 128-VGPR budget (R11 live set measured 108, fits).
//   This is why the R7-R9 1024-thread attempts spilled (small LDS ->
//   8-waves/EU target -> 64-VGPR clamp) and this one shouldn't.
//   Ladder: 1 wave/SIMD = 67.4 us (R10), 2 = 56.5 us (R11), this = 4.
//   Phase A: stream all 512 rows (batch-8 -> 16 loads in flight/thread),
//   compute dist + S partials; rows < 288 also ds_written to LDS.
//   Phase B: rows < 288 from LDS (free); rows >= 288 re-read via L3.
__global__ __launch_bounds__(1024) void som_fused(
    const float* __restrict__ X,
    const float* __restrict__ W,
    float* __restrict__ dist,
    float* __restrict__ outW)
{
    const int j    = blockIdx.x;          // 0..511 column
    const int t    = threadIdx.x;
    const int wave = t >> 6;              // 0..15
    const int lane = t & 63;
    const int g    = lane >> 5;           // row-subgroup 0..1
    const int i32  = lane & 31;           // d-slice index
    const int d0   = i32 * 4;             // floats [d0, d0+4)
    const int rb   = wave * 2 + g;        // row-in-group 0..31; b = grp*32 + rb

    __shared__ float ldsW[LDS_ROWS * D_DIM];   // 147456 B
    __shared__ float sacc[16][D_DIM];          // 8192 B
    __shared__ float sS[D_DIM];                // 512 B

    f32x4 acc = {0.f, 0.f, 0.f, 0.f};

    // ---------------- phase A: 2 batches x 8 groups (256 rows/batch) ----------------
    #pragma unroll
    for (int bt = 0; bt < 2; ++bt) {
        f32x4 wv[8], xv[8];
        #pragma unroll
        for (int u = 0; u < 8; ++u) {
            const int b = (bt * 8 + u) * 32 + rb;
            wv[u] = *(const f32x4*)(W + ((size_t)b * O_DIM + j) * D_DIM + d0);
            xv[u] = *(const f32x4*)(X + (size_t)b * D_DIM + d0);
        }
        #pragma unroll
        for (int u = 0; u < 8; ++u) {
            const int b = (bt * 8 + u) * 32 + rb;
            const f32x4 dx = wv[u] - xv[u];
            float sum = dx.x * dx.x;
            sum = fmaf(dx.y, dx.y, sum);
            sum = fmaf(dx.z, dx.z, sum);
            sum = fmaf(dx.w, dx.w, sum);
            // reduce across the 32 lanes of this row
            sum += __shfl_xor(sum, 1, 64);
            sum += __shfl_xor(sum, 2, 64);
            sum += __shfl_xor(sum, 4, 64);
            sum += __shfl_xor(sum, 8, 64);
            sum += __shfl_xor(sum, 16, 64);

            if (i32 == 0) dist[(size_t)b * O_DIM + j] = sum;

            const float c = LR * __expf(-sum * INV2SIG2);
            acc -= c * dx;                    // += c * (x - w)

            if (b < LDS_ROWS)                 // group-uniform (288 % 32 == 0)
                *(f32x4*)(&ldsW[b * D_DIM + d0]) = wv[u];
        }
    }

    // ---- fold the two row-subgroups (lane ^ 32) ----
    acc.x += __shfl_xor(acc.x, 32, 64);
    acc.y += __shfl_xor(acc.y, 32, 64);
    acc.z += __shfl_xor(acc.z, 32, 64);
    acc.w += __shfl_xor(acc.w, 32, 64);

    if (lane < 32) *(f32x4*)(&sacc[wave][d0]) = acc;
    __syncthreads();
    if (t < D_DIM) {
        float v = sacc[0][t];
        #pragma unroll
        for (int w = 1; w < 16; ++w) v += sacc[w][t];
        sS[t] = v;
    }
    __syncthreads();
    const f32x4 s4 = *(const f32x4*)(sS + d0);

    // ---------------- phase B-lower: rows 0..287 from LDS ----------------
    #pragma unroll 3
    for (int grp = 0; grp < LDS_GRPS; ++grp) {
        const int b = grp * 32 + rb;
        const f32x4 wv = *(const f32x4*)(&ldsW[b * D_DIM + d0]);
        __builtin_nontemporal_store(
            wv + s4, (f32x4*)(outW + ((size_t)b * O_DIM + j) * D_DIM + d0));
    }
    // ---------------- phase B-upper: rows 288..511 from L3, batch 7 ----------------
    {
        f32x4 wx[7];
        #pragma unroll
        for (int u = 0; u < 7; ++u) {
            const int b = (LDS_GRPS + u) * 32 + rb;
            wx[u] = *(const f32x4*)(W + ((size_t)b * O_DIM + j) * D_DIM + d0);
        }
        #pragma unroll
        for (int u = 0; u < 7; ++u) {
            const int b = (LDS_GRPS + u) * 32 + rb;
            __builtin_nontemporal_store(
                wx[u] + s4, (f32x4*)(outW + ((size_t)b * O_DIM + j) * D_DIM + d0));
        }
    }
}

// row-wise argmin over j for each b
__global__ __launch_bounds__(64) void som_argmin(
    const float* __restrict__ dist,
    float* __restrict__ out)
{
    const int b = blockIdx.x;
    const int lane = threadIdx.x;
    unsigned long long best = ~0ull;
    #pragma unroll
    for (int k = 0; k < 8; ++k) {
        const int jj = k * 64 + lane;
        const float s = dist[(size_t)b * O_DIM + jj];
        const unsigned long long key =
            ((unsigned long long)__float_as_uint(s) << 32) | (unsigned int)jj;
        best = key < best ? key : best;
    }
    #pragma unroll
    for (int m = 32; m >= 1; m >>= 1) {
        const unsigned long long o = __shfl_xor(best, m, 64);
        best = o < best ? o : best;
    }
    if (lane == 0) out[b] = (float)(unsigned int)(best & 0xFFFFFFFFull);
}

// ---------------- fallback path (atomics, small ws) ----------------

__global__ __launch_bounds__(256) void som_pass1_atomic(
    const float* __restrict__ X, const float* __restrict__ W,
    float* __restrict__ S, unsigned long long* __restrict__ wkey)
{
    const int j = blockIdx.x >> 2, chunk = blockIdx.x & 3;
    const int wave = threadIdx.x >> 6, lane = threadIdx.x & 63;
    const int d0 = lane * 2;
    float accx = 0.f, accy = 0.f;
    const int b_end = chunk * 128 + 128;
    for (int b = chunk * 128 + wave; b < b_end; b += 4) {
        const float2 w2 = *(const float2*)(W + ((size_t)b * O_DIM + j) * D_DIM + d0);
        const float2 x2 = *(const float2*)(X + (size_t)b * D_DIM + d0);
        const float dx = w2.x - x2.x, dy = w2.y - x2.y;
        float s = dx * dx + dy * dy;
        #pragma unroll
        for (int m = 32; m >= 1; m >>= 1) s += __shfl_xor(s, m, 64);
        if (lane == 0)
            atomicMin(&wkey[b], ((unsigned long long)__float_as_uint(s) << 32) | (unsigned)j);
        const float c = LR * __expf(-s * INV2SIG2);
        accx -= c * dx; accy -= c * dy;
    }
    __shared__ float sacc[D_DIM];
    if (threadIdx.x < D_DIM) sacc[threadIdx.x] = 0.f;
    __syncthreads();
    atomicAdd(&sacc[d0], accx); atomicAdd(&sacc[d0 + 1], accy);
    __syncthreads();
    if (threadIdx.x < D_DIM) atomicAdd(&S[(size_t)j * D_DIM + threadIdx.x], sacc[threadIdx.x]);
}

__global__ __launch_bounds__(256) void som_pass2_atomic(
    const float* __restrict__ W, const float* __restrict__ S,
    const unsigned long long* __restrict__ wkey, float* __restrict__ out)
{
    const size_t tid = (size_t)blockIdx.x * blockDim.x + threadIdx.x;
    if (tid < O_DIM) out[tid] = (float)(unsigned int)(wkey[tid] & 0xFFFFFFFFull);
    float* __restrict__ outW = out + O_DIM;
    const size_t total4 = (size_t)O_DIM * O_DIM * D_DIM / 4;
    const size_t stride = (size_t)gridDim.x * blockDim.x;
    for (size_t i = tid; i < total4; i += stride) {
        const size_t e = i * 4;
        const float4 w4 = *(const float4*)(W + e);
        const float4 s4 = *(const float4*)(S + (e & (size_t)(O_DIM * D_DIM - 1)));
        float4 o4 = {w4.x + s4.x, w4.y + s4.y, w4.z + s4.z, w4.w + s4.w};
        *(float4*)(outW + e) = o4;
    }
}

extern "C" void kernel_launch(void* const* d_in, const int* in_sizes, int n_in,
                              void* d_out, int out_size, void* d_ws, size_t ws_size,
                              hipStream_t stream)
{
    const float* X = (const float*)d_in[0];   // (512, 128)
    const float* W = (const float*)d_in[1];   // (512, 512, 128)
    float* out = (float*)d_out;               // 512 winners + 512*512*128 weights

    const size_t DIST_BYTES = (size_t)O_DIM * O_DIM * sizeof(float);   // 1 MiB

    if (ws_size >= DIST_BYTES) {
        float* dist = (float*)d_ws;
        som_fused <<<dim3(512), dim3(1024), 0, stream>>>(X, W, dist, out + O_DIM);
        som_argmin<<<dim3(512), dim3(64),   0, stream>>>(dist, out);
    } else {
        float* S = (float*)d_ws;
        unsigned long long* wkey =
            (unsigned long long*)((char*)d_ws + (size_t)O_DIM * D_DIM * sizeof(float));
        hipMemsetAsync(S, 0, (size_t)O_DIM * D_DIM * sizeof(float), stream);
        hipMemsetAsync(wkey, 0xFF, (size_t)O_DIM * sizeof(unsigned long long), stream);
        som_pass1_atomic<<<dim3(2048), dim3(256), 0, stream>>>(X, W, S, wkey);
        som_pass2_atomic<<<dim3(2048), dim3(256), 0, stream>>>(W, S, wkey, out);
    }
}